// Round 1
// baseline (1051.228 us; speedup 1.0000x reference)
//
#include <hip/hip_runtime.h>
#include <math.h>

#define N_NODES 50000
#define E_EDGES 600000
#define IN_DIM  384
#define HID     128
#define HYP     256

// ---------------- graph preprocessing ----------------

__global__ void k_deg(const int* __restrict__ dst, int* __restrict__ deg) {
    int i = blockIdx.x * blockDim.x + threadIdx.x;
    if (i < E_EDGES) atomicAdd(&deg[dst[i]], 1);
}

__global__ __launch_bounds__(1024) void k_scan(const int* __restrict__ deg, int* __restrict__ row_start,
                                               float* __restrict__ dinv) {
    __shared__ int part[1024];
    int tid = threadIdx.x;
    const int chunk = (N_NODES + 1023) >> 10;  // 49
    int s = tid * chunk;
    int e = min(N_NODES, s + chunk);
    int sum = 0;
    for (int i = s; i < e; ++i) sum += deg[i];
    part[tid] = sum;
    __syncthreads();
    for (int off = 1; off < 1024; off <<= 1) {
        int t = (tid >= off) ? part[tid - off] : 0;
        __syncthreads();
        part[tid] += t;
        __syncthreads();
    }
    int base = part[tid] - sum;  // exclusive prefix
    for (int i = s; i < e; ++i) {
        int d = deg[i];
        row_start[i] = base;
        base += d;
        dinv[i] = (d > 0) ? rsqrtf((float)d) : 0.0f;
    }
    if (tid == 0) row_start[N_NODES] = E_EDGES;
}

__global__ void k_fill(const int* __restrict__ src, const int* __restrict__ dst,
                       const int* __restrict__ row_start, int* __restrict__ cnt,
                       const float* __restrict__ dinv,
                       int* __restrict__ csr_src, float* __restrict__ csr_w) {
    int i = blockIdx.x * blockDim.x + threadIdx.x;
    if (i < E_EDGES) {
        int d = dst[i], s = src[i];
        int pos = row_start[d] + atomicAdd(&cnt[d], 1);
        csr_src[pos] = s;
        csr_w[pos] = dinv[s] * dinv[d];
    }
}

// ---------------- x_emb = x @ w_feat + b (8 rows / block) ----------------

__global__ __launch_bounds__(128) void k_emb(const float* __restrict__ x, const float* __restrict__ wf,
                                             const float* __restrict__ bf,
                                             float* __restrict__ x_emb, float* __restrict__ accb) {
    __shared__ float xl[IN_DIM * 8];  // [k][r], 12 KB
    int n0 = blockIdx.x * 8;
    int tid = threadIdx.x;
    for (int idx = tid; idx < IN_DIM * 8; idx += 128) {
        int r = idx / IN_DIM;
        int k = idx - r * IN_DIM;
        xl[k * 8 + r] = x[(size_t)(n0 + r) * IN_DIM + k];
    }
    __syncthreads();
    float acc[8];
#pragma unroll
    for (int r = 0; r < 8; ++r) acc[r] = 0.0f;
#pragma unroll 4
    for (int k = 0; k < IN_DIM; ++k) {
        float w = wf[k * HID + tid];
        float4 p = *reinterpret_cast<const float4*>(&xl[k * 8]);
        float4 q = *reinterpret_cast<const float4*>(&xl[k * 8 + 4]);
        acc[0] = fmaf(p.x, w, acc[0]);
        acc[1] = fmaf(p.y, w, acc[1]);
        acc[2] = fmaf(p.z, w, acc[2]);
        acc[3] = fmaf(p.w, w, acc[3]);
        acc[4] = fmaf(q.x, w, acc[4]);
        acc[5] = fmaf(q.y, w, acc[5]);
        acc[6] = fmaf(q.z, w, acc[6]);
        acc[7] = fmaf(q.w, w, acc[7]);
    }
    float b = bf[tid];
#pragma unroll
    for (int r = 0; r < 8; ++r) {
        float v = acc[r] + b;
        size_t o = (size_t)(n0 + r) * HID + tid;
        x_emb[o] = v;
        accb[o] = v;  // layer-0 term of the mean
    }
}

// ---------------- one LightGCN layer: nxt[n] = sum_{e->n} w_e * cur[src_e]; accb += nxt ----------------

__global__ __launch_bounds__(128) void k_prop(const float* __restrict__ cur, float* __restrict__ nxt,
                                              float* __restrict__ accb,
                                              const int* __restrict__ row_start,
                                              const int* __restrict__ csr_src, const float* __restrict__ csr_w) {
    int n = blockIdx.x;
    int tid = threadIdx.x;
    int s = row_start[n];
    int e = row_start[n + 1];
    float acc = 0.0f;
    for (int i = s; i < e; ++i) {
        int sc = csr_src[i];
        float w = csr_w[i];
        acc = fmaf(cur[(size_t)sc * HID + tid], w, acc);
    }
    size_t o = (size_t)n * HID + tid;
    nxt[o] = acc;
    accb[o] += acc;
}

// ---------------- Hm = softmax((x_emb @ w_hyper + g)/tau) (8 rows / block, 256 thr) ----------------

__global__ __launch_bounds__(256) void k_soft(const float* __restrict__ x_emb, const float* __restrict__ wh,
                                              const float* __restrict__ gu, float* __restrict__ Hm) {
    __shared__ float xl[HID * 8];  // [k][r], 4 KB
    __shared__ float red[8 * 4];
    int n0 = blockIdx.x * 8;
    int tid = threadIdx.x;
    int lane = tid & 63;
    int wid = tid >> 6;
    for (int idx = tid; idx < HID * 8; idx += 256) {
        int r = idx >> 7;
        int k = idx & 127;
        xl[k * 8 + r] = x_emb[(size_t)(n0 + r) * HID + k];
    }
    __syncthreads();
    float acc[8];
#pragma unroll
    for (int r = 0; r < 8; ++r) acc[r] = 0.0f;
#pragma unroll 4
    for (int k = 0; k < HID; ++k) {
        float w = wh[k * HYP + tid];
        float4 p = *reinterpret_cast<const float4*>(&xl[k * 8]);
        float4 q = *reinterpret_cast<const float4*>(&xl[k * 8 + 4]);
        acc[0] = fmaf(p.x, w, acc[0]);
        acc[1] = fmaf(p.y, w, acc[1]);
        acc[2] = fmaf(p.z, w, acc[2]);
        acc[3] = fmaf(p.w, w, acc[3]);
        acc[4] = fmaf(q.x, w, acc[4]);
        acc[5] = fmaf(q.y, w, acc[5]);
        acc[6] = fmaf(q.z, w, acc[6]);
        acc[7] = fmaf(q.w, w, acc[7]);
    }
    float y[8];
#pragma unroll
    for (int r = 0; r < 8; ++r) {
        float u = gu[(size_t)(n0 + r) * HYP + tid];
        float g = -logf(-logf(u + 1e-10f) + 1e-10f);
        y[r] = (acc[r] + g) * 2.0f;  // 1/tau = 2
    }
    // block max per row
#pragma unroll
    for (int r = 0; r < 8; ++r) {
        float v = y[r];
        for (int off = 32; off >= 1; off >>= 1) v = fmaxf(v, __shfl_xor(v, off));
        if (lane == 0) red[r * 4 + wid] = v;
    }
    __syncthreads();
    float m[8];
#pragma unroll
    for (int r = 0; r < 8; ++r)
        m[r] = fmaxf(fmaxf(red[r * 4 + 0], red[r * 4 + 1]), fmaxf(red[r * 4 + 2], red[r * 4 + 3]));
    __syncthreads();
#pragma unroll
    for (int r = 0; r < 8; ++r) {
        y[r] = __expf(y[r] - m[r]);
        float v = y[r];
        for (int off = 32; off >= 1; off >>= 1) v += __shfl_xor(v, off);
        if (lane == 0) red[r * 4 + wid] = v;
    }
    __syncthreads();
#pragma unroll
    for (int r = 0; r < 8; ++r) {
        float s = red[r * 4 + 0] + red[r * 4 + 1] + red[r * 4 + 2] + red[r * 4 + 3];
        Hm[(size_t)(n0 + r) * HYP + tid] = y[r] / s;
    }
}

// ---------------- lat = Hm^T @ x_emb (split-K, 64x64 tiles, atomic combine) ----------------

__global__ __launch_bounds__(256) void k_lat(const float* __restrict__ Hm, const float* __restrict__ x_emb,
                                             float* __restrict__ lat) {
    __shared__ float A[8 * 64];
    __shared__ float B[8 * 64];
    int bx = blockIdx.x;
    int tile = bx & 7;
    int kc = bx >> 3;
    int KC = (int)(gridDim.x >> 3);
    int h0 = (tile & 3) * 64;
    int d0 = (tile >> 2) * 64;
    int chunk = (N_NODES + KC - 1) / KC;
    int start = kc * chunk;
    int end = min(N_NODES, start + chunk);
    int tid = threadIdx.x;
    int hl = (tid & 15) * 4;
    int dl = (tid >> 4) * 4;
    float acc[16];
#pragma unroll
    for (int i = 0; i < 16; ++i) acc[i] = 0.0f;
    for (int n0 = start; n0 < end; n0 += 8) {
#pragma unroll
        for (int t = 0; t < 4; ++t) {
            int idx = tid + t * 256;
            int half = idx >> 9;
            int r = (idx >> 6) & 7;
            int c = idx & 63;
            int n = n0 + r;
            float v = 0.0f;
            if (n < end) v = half ? x_emb[(size_t)n * HID + d0 + c] : Hm[(size_t)n * HYP + h0 + c];
            if (half) B[r * 64 + c] = v;
            else A[r * 64 + c] = v;
        }
        __syncthreads();
#pragma unroll
        for (int r = 0; r < 8; ++r) {
            float4 av = *reinterpret_cast<const float4*>(&A[r * 64 + hl]);
            float4 bv = *reinterpret_cast<const float4*>(&B[r * 64 + dl]);
            float aa[4] = {av.x, av.y, av.z, av.w};
            float bb[4] = {bv.x, bv.y, bv.z, bv.w};
#pragma unroll
            for (int i = 0; i < 4; ++i)
#pragma unroll
                for (int j = 0; j < 4; ++j) acc[i * 4 + j] = fmaf(aa[i], bb[j], acc[i * 4 + j]);
        }
        __syncthreads();
    }
#pragma unroll
    for (int i = 0; i < 4; ++i)
#pragma unroll
        for (int j = 0; j < 4; ++j)
            atomicAdd(&lat[(size_t)(h0 + hl + i) * HID + (d0 + dl + j)], acc[i * 4 + j]);
}

// ---------------- tail: hyper_out = Hm @ lat; normalize; final; both ReLU heads ----------------

__global__ __launch_bounds__(128) void k_tail(const float* __restrict__ Hm, const float* __restrict__ lat,
                                              const float* __restrict__ accb,
                                              const float* __restrict__ wv, const float* __restrict__ bv,
                                              const float* __restrict__ wt, const float* __restrict__ bt,
                                              float* __restrict__ out_final, float* __restrict__ out_vis,
                                              float* __restrict__ out_txt) {
    __shared__ float hl[HYP * 8];  // 8 KB, [h][r]
    __shared__ float fl[HID * 8];  // 4 KB, [k][r]
    __shared__ float red[8 * 2];
    int n0 = blockIdx.x * 8;
    int tid = threadIdx.x;
    int lane = tid & 63;
    int wid = tid >> 6;
    for (int idx = tid; idx < HYP * 8; idx += 128) {
        int r = idx >> 8;
        int h = idx & 255;
        hl[h * 8 + r] = Hm[(size_t)(n0 + r) * HYP + h];
    }
    __syncthreads();
    float acc[8];
#pragma unroll
    for (int r = 0; r < 8; ++r) acc[r] = 0.0f;
#pragma unroll 2
    for (int h = 0; h < HYP; ++h) {
        float l = lat[h * HID + tid];
        float4 p = *reinterpret_cast<const float4*>(&hl[h * 8]);
        float4 q = *reinterpret_cast<const float4*>(&hl[h * 8 + 4]);
        acc[0] = fmaf(p.x, l, acc[0]);
        acc[1] = fmaf(p.y, l, acc[1]);
        acc[2] = fmaf(p.z, l, acc[2]);
        acc[3] = fmaf(p.w, l, acc[3]);
        acc[4] = fmaf(q.x, l, acc[4]);
        acc[5] = fmaf(q.y, l, acc[5]);
        acc[6] = fmaf(q.z, l, acc[6]);
        acc[7] = fmaf(q.w, l, acc[7]);
    }
    // row L2 norms across 128 threads (2 waves)
#pragma unroll
    for (int r = 0; r < 8; ++r) {
        float v = acc[r] * acc[r];
        for (int off = 32; off >= 1; off >>= 1) v += __shfl_xor(v, off);
        if (lane == 0) red[r * 2 + wid] = v;
    }
    __syncthreads();
    float fin[8];
#pragma unroll
    for (int r = 0; r < 8; ++r) {
        float ss = red[r * 2] + red[r * 2 + 1];
        float nr = fmaxf(sqrtf(ss), 1e-12f);
        float f = accb[(size_t)(n0 + r) * HID + tid] * 0.25f + 0.1f * (acc[r] / nr);
        fin[r] = f;
        out_final[(size_t)(n0 + r) * HID + tid] = f;
    }
    // stage final rows transposed for the heads
    *reinterpret_cast<float4*>(&fl[tid * 8 + 0]) = make_float4(fin[0], fin[1], fin[2], fin[3]);
    *reinterpret_cast<float4*>(&fl[tid * 8 + 4]) = make_float4(fin[4], fin[5], fin[6], fin[7]);
    __syncthreads();
    float av[8], at[8];
#pragma unroll
    for (int r = 0; r < 8; ++r) { av[r] = 0.0f; at[r] = 0.0f; }
#pragma unroll 2
    for (int k = 0; k < HID; ++k) {
        float v = wv[k * HID + tid];
        float t = wt[k * HID + tid];
        float4 p = *reinterpret_cast<const float4*>(&fl[k * 8]);
        float4 q = *reinterpret_cast<const float4*>(&fl[k * 8 + 4]);
        av[0] = fmaf(p.x, v, av[0]); at[0] = fmaf(p.x, t, at[0]);
        av[1] = fmaf(p.y, v, av[1]); at[1] = fmaf(p.y, t, at[1]);
        av[2] = fmaf(p.z, v, av[2]); at[2] = fmaf(p.z, t, at[2]);
        av[3] = fmaf(p.w, v, av[3]); at[3] = fmaf(p.w, t, at[3]);
        av[4] = fmaf(q.x, v, av[4]); at[4] = fmaf(q.x, t, at[4]);
        av[5] = fmaf(q.y, v, av[5]); at[5] = fmaf(q.y, t, at[5]);
        av[6] = fmaf(q.z, v, av[6]); at[6] = fmaf(q.z, t, at[6]);
        av[7] = fmaf(q.w, v, av[7]); at[7] = fmaf(q.w, t, at[7]);
    }
    float bvv = bv[tid], btt = bt[tid];
#pragma unroll
    for (int r = 0; r < 8; ++r) {
        out_vis[(size_t)(n0 + r) * HID + tid] = fmaxf(av[r] + bvv, 0.0f);
        out_txt[(size_t)(n0 + r) * HID + tid] = fmaxf(at[r] + btt, 0.0f);
    }
}

// ---------------- launch ----------------

extern "C" void kernel_launch(void* const* d_in, const int* in_sizes, int n_in,
                              void* d_out, int out_size, void* d_ws, size_t ws_size,
                              hipStream_t stream) {
    const float* x      = (const float*)d_in[0];
    const int*   ei     = (const int*)d_in[1];
    const float* gu     = (const float*)d_in[2];
    const float* w_feat = (const float*)d_in[3];
    const float* b_feat = (const float*)d_in[4];
    const float* w_hyp  = (const float*)d_in[5];
    const float* w_vis  = (const float*)d_in[6];
    const float* b_vis  = (const float*)d_in[7];
    const float* w_txt  = (const float*)d_in[8];
    const float* b_txt  = (const float*)d_in[9];
    float* out = (float*)d_out;

    const int* srcv = ei;
    const int* dstv = ei + E_EDGES;

    char* p = (char*)d_ws;
    int*   deg     = (int*)p;   p += (size_t)N_NODES * 4;
    int*   cnt     = (int*)p;   p += (size_t)N_NODES * 4;
    float* lat     = (float*)p; p += (size_t)HYP * HID * 4;
    int*   rs      = (int*)p;   p += (size_t)(N_NODES + 1) * 4;
    float* dinv    = (float*)p; p += (size_t)N_NODES * 4;
    int*   csr_src = (int*)p;   p += (size_t)E_EDGES * 4;
    float* csr_w   = (float*)p; p += (size_t)E_EDGES * 4;
    float* x_emb   = (float*)p; p += (size_t)N_NODES * HID * 4;
    float* bufA    = (float*)p; p += (size_t)N_NODES * HID * 4;
    float* bufB    = (float*)p; p += (size_t)N_NODES * HID * 4;
    float* accb    = (float*)p; p += (size_t)N_NODES * HID * 4;
    float* Hm      = (float*)p; p += (size_t)N_NODES * HYP * 4;

    // zero: deg, cnt, lat (contiguous at the head of ws)
    hipMemsetAsync(d_ws, 0, (size_t)(2 * N_NODES + HYP * HID) * 4, stream);

    k_deg<<<(E_EDGES + 255) / 256, 256, 0, stream>>>(dstv, deg);
    k_scan<<<1, 1024, 0, stream>>>(deg, rs, dinv);
    k_fill<<<(E_EDGES + 255) / 256, 256, 0, stream>>>(srcv, dstv, rs, cnt, dinv, csr_src, csr_w);
    k_emb<<<N_NODES / 8, 128, 0, stream>>>(x, w_feat, b_feat, x_emb, accb);
    k_prop<<<N_NODES, 128, 0, stream>>>(x_emb, bufA, accb, rs, csr_src, csr_w);
    k_prop<<<N_NODES, 128, 0, stream>>>(bufA, bufB, accb, rs, csr_src, csr_w);
    k_prop<<<N_NODES, 128, 0, stream>>>(bufB, bufA, accb, rs, csr_src, csr_w);
    k_soft<<<N_NODES / 8, 256, 0, stream>>>(x_emb, w_hyp, gu, Hm);
    k_lat<<<8 * 128, 256, 0, stream>>>(Hm, x_emb, lat);
    k_tail<<<N_NODES / 8, 128, 0, stream>>>(Hm, lat, accb, w_vis, b_vis, w_txt, b_txt,
                                            out, out + (size_t)N_NODES * HID, out + (size_t)2 * N_NODES * HID);
}

// Round 3
// 970.495 us; speedup vs baseline: 1.0832x; 1.0832x over previous
//
#include <hip/hip_runtime.h>
#include <math.h>

#define N_NODES 50000
#define E_EDGES 600000
#define IN_DIM  384
#define HID     128
#define HYP     256

// ---------------- graph preprocessing ----------------

__global__ void k_deg(const int* __restrict__ dst, int* __restrict__ deg) {
    int i = blockIdx.x * blockDim.x + threadIdx.x;
    if (i < E_EDGES) atomicAdd(&deg[dst[i]], 1);
}

__global__ __launch_bounds__(1024) void k_scan(const int* __restrict__ deg, int* __restrict__ row_start,
                                               float* __restrict__ dinv) {
    __shared__ int part[1024];
    int tid = threadIdx.x;
    const int chunk = (N_NODES + 1023) >> 10;  // 49
    int s = tid * chunk;
    int e = min(N_NODES, s + chunk);
    int sum = 0;
    for (int i = s; i < e; ++i) sum += deg[i];
    part[tid] = sum;
    __syncthreads();
    for (int off = 1; off < 1024; off <<= 1) {
        int t = (tid >= off) ? part[tid - off] : 0;
        __syncthreads();
        part[tid] += t;
        __syncthreads();
    }
    int base = part[tid] - sum;  // exclusive prefix
    for (int i = s; i < e; ++i) {
        int d = deg[i];
        row_start[i] = base;
        base += d;
        dinv[i] = (d > 0) ? rsqrtf((float)d) : 0.0f;
    }
    if (tid == 0) row_start[N_NODES] = E_EDGES;
}

__global__ void k_fill(const int* __restrict__ src, const int* __restrict__ dst,
                       const int* __restrict__ row_start, int* __restrict__ cnt,
                       const float* __restrict__ dinv,
                       int* __restrict__ csr_src, float* __restrict__ csr_w) {
    int i = blockIdx.x * blockDim.x + threadIdx.x;
    if (i < E_EDGES) {
        int d = dst[i], s = src[i];
        int pos = row_start[d] + atomicAdd(&cnt[d], 1);
        csr_src[pos] = s;
        csr_w[pos] = dinv[s] * dinv[d];
    }
}

// ---------------- x_emb = x @ w_feat + b (16 rows / block, 128 thr, 2 cols/thr) ----------------

__global__ __launch_bounds__(128) void k_emb(const float* __restrict__ x, const float* __restrict__ wf,
                                             const float* __restrict__ bf,
                                             float* __restrict__ x_emb, float* __restrict__ accb) {
    __shared__ float xl[IN_DIM * 16];  // [k][r], 24 KB
    int n0 = blockIdx.x * 16;
    int tid = threadIdx.x;
    int lane = tid & 63;
    int w8 = (tid >> 6) * 8;   // row group for this wave
    int c2 = lane * 2;         // column pair
    // stage: conflict-free LDS writes; global reads 16B-granular (L2-cached)
#pragma unroll
    for (int it = 0; it < 12; ++it) {
        int idx4 = tid + it * 128;           // 0..1535
        int r = idx4 & 15;
        int k4 = idx4 >> 4;                  // 0..95
        float4 v = *reinterpret_cast<const float4*>(&x[(size_t)(n0 + r) * IN_DIM + 4 * k4]);
        xl[(4 * k4 + 0) * 16 + r] = v.x;
        xl[(4 * k4 + 1) * 16 + r] = v.y;
        xl[(4 * k4 + 2) * 16 + r] = v.z;
        xl[(4 * k4 + 3) * 16 + r] = v.w;
    }
    __syncthreads();
    float acc[8][2];
#pragma unroll
    for (int r = 0; r < 8; ++r) { acc[r][0] = 0.0f; acc[r][1] = 0.0f; }
    for (int k = 0; k < IN_DIM; k += 4) {
        float2 wv[4];
#pragma unroll
        for (int j = 0; j < 4; ++j)
            wv[j] = *reinterpret_cast<const float2*>(&wf[(size_t)(k + j) * HID + c2]);
#pragma unroll
        for (int j = 0; j < 4; ++j) {
            float4 p = *reinterpret_cast<const float4*>(&xl[(k + j) * 16 + w8]);
            float4 q = *reinterpret_cast<const float4*>(&xl[(k + j) * 16 + w8 + 4]);
            acc[0][0] = fmaf(p.x, wv[j].x, acc[0][0]); acc[0][1] = fmaf(p.x, wv[j].y, acc[0][1]);
            acc[1][0] = fmaf(p.y, wv[j].x, acc[1][0]); acc[1][1] = fmaf(p.y, wv[j].y, acc[1][1]);
            acc[2][0] = fmaf(p.z, wv[j].x, acc[2][0]); acc[2][1] = fmaf(p.z, wv[j].y, acc[2][1]);
            acc[3][0] = fmaf(p.w, wv[j].x, acc[3][0]); acc[3][1] = fmaf(p.w, wv[j].y, acc[3][1]);
            acc[4][0] = fmaf(q.x, wv[j].x, acc[4][0]); acc[4][1] = fmaf(q.x, wv[j].y, acc[4][1]);
            acc[5][0] = fmaf(q.y, wv[j].x, acc[5][0]); acc[5][1] = fmaf(q.y, wv[j].y, acc[5][1]);
            acc[6][0] = fmaf(q.z, wv[j].x, acc[6][0]); acc[6][1] = fmaf(q.z, wv[j].y, acc[6][1]);
            acc[7][0] = fmaf(q.w, wv[j].x, acc[7][0]); acc[7][1] = fmaf(q.w, wv[j].y, acc[7][1]);
        }
    }
    float2 b = *reinterpret_cast<const float2*>(&bf[c2]);
#pragma unroll
    for (int r = 0; r < 8; ++r) {
        float2 v;
        v.x = acc[r][0] + b.x;
        v.y = acc[r][1] + b.y;
        size_t o = (size_t)(n0 + w8 + r) * HID + c2;
        *reinterpret_cast<float2*>(&x_emb[o]) = v;
        *reinterpret_cast<float2*>(&accb[o]) = v;
    }
}

// ---------------- one LightGCN layer (4 nodes / block, 32 lanes x float4, unroll 4) ----------------

__device__ __forceinline__ void fma4(float4& a, const float4& v, float s) {
    a.x = fmaf(v.x, s, a.x);
    a.y = fmaf(v.y, s, a.y);
    a.z = fmaf(v.z, s, a.z);
    a.w = fmaf(v.w, s, a.w);
}

__global__ __launch_bounds__(128) void k_prop(const float* __restrict__ cur, float* __restrict__ nxt,
                                              float* __restrict__ accb,
                                              const int* __restrict__ row_start,
                                              const int* __restrict__ csr_src, const float* __restrict__ csr_w) {
    int tid = threadIdx.x;
    int n = blockIdx.x * 4 + (tid >> 5);
    int c4 = (tid & 31) * 4;
    int s = row_start[n];
    int e = row_start[n + 1];
    float4 a0 = {0.f, 0.f, 0.f, 0.f}, a1 = a0, a2 = a0, a3 = a0;
    int i = s;
    for (; i + 4 <= e; i += 4) {
        int s0 = csr_src[i], s1 = csr_src[i + 1], s2 = csr_src[i + 2], s3 = csr_src[i + 3];
        float w0 = csr_w[i], w1 = csr_w[i + 1], w2 = csr_w[i + 2], w3 = csr_w[i + 3];
        float4 v0 = *reinterpret_cast<const float4*>(&cur[(size_t)s0 * HID + c4]);
        float4 v1 = *reinterpret_cast<const float4*>(&cur[(size_t)s1 * HID + c4]);
        float4 v2 = *reinterpret_cast<const float4*>(&cur[(size_t)s2 * HID + c4]);
        float4 v3 = *reinterpret_cast<const float4*>(&cur[(size_t)s3 * HID + c4]);
        fma4(a0, v0, w0); fma4(a1, v1, w1); fma4(a2, v2, w2); fma4(a3, v3, w3);
    }
    for (; i < e; ++i) {
        int s0 = csr_src[i];
        float w0 = csr_w[i];
        float4 v0 = *reinterpret_cast<const float4*>(&cur[(size_t)s0 * HID + c4]);
        fma4(a0, v0, w0);
    }
    a0.x += a1.x + a2.x + a3.x;
    a0.y += a1.y + a2.y + a3.y;
    a0.z += a1.z + a2.z + a3.z;
    a0.w += a1.w + a2.w + a3.w;
    size_t o = (size_t)n * HID + c4;
    *reinterpret_cast<float4*>(&nxt[o]) = a0;
    float4 ac = *reinterpret_cast<const float4*>(&accb[o]);
    ac.x += a0.x; ac.y += a0.y; ac.z += a0.z; ac.w += a0.w;
    *reinterpret_cast<float4*>(&accb[o]) = ac;
}

// ---------------- Hm = softmax((x_emb @ w_hyper + g)/tau) (16 rows / block, 128 thr, 2 cols/thr) ----------------

__global__ __launch_bounds__(128) void k_soft(const float* __restrict__ x_emb, const float* __restrict__ wh,
                                              const float* __restrict__ gu, float* __restrict__ Hm) {
    __shared__ float xl[HID * 16];  // [k][r], 8 KB
    __shared__ float redA[2][16];
    __shared__ float redB[2][16];
    int n0 = blockIdx.x * 16;
    int tid = threadIdx.x;
    int lane = tid & 63;
    int w = tid >> 6;
    int c2 = tid * 2;  // column pair 0..254
#pragma unroll
    for (int it = 0; it < 4; ++it) {
        int idx4 = tid + it * 128;  // 0..511
        int r = idx4 & 15;
        int k4 = idx4 >> 4;         // 0..31
        float4 v = *reinterpret_cast<const float4*>(&x_emb[(size_t)(n0 + r) * HID + 4 * k4]);
        xl[(4 * k4 + 0) * 16 + r] = v.x;
        xl[(4 * k4 + 1) * 16 + r] = v.y;
        xl[(4 * k4 + 2) * 16 + r] = v.z;
        xl[(4 * k4 + 3) * 16 + r] = v.w;
    }
    __syncthreads();
    float acc[16][2];
#pragma unroll
    for (int r = 0; r < 16; ++r) { acc[r][0] = 0.0f; acc[r][1] = 0.0f; }
    for (int k = 0; k < HID; k += 4) {
        float2 wv[4];
#pragma unroll
        for (int j = 0; j < 4; ++j)
            wv[j] = *reinterpret_cast<const float2*>(&wh[(size_t)(k + j) * HYP + c2]);
#pragma unroll
        for (int j = 0; j < 4; ++j) {
            float4 p0 = *reinterpret_cast<const float4*>(&xl[(k + j) * 16 + 0]);
            float4 p1 = *reinterpret_cast<const float4*>(&xl[(k + j) * 16 + 4]);
            float4 p2 = *reinterpret_cast<const float4*>(&xl[(k + j) * 16 + 8]);
            float4 p3 = *reinterpret_cast<const float4*>(&xl[(k + j) * 16 + 12]);
            acc[0][0]  = fmaf(p0.x, wv[j].x, acc[0][0]);  acc[0][1]  = fmaf(p0.x, wv[j].y, acc[0][1]);
            acc[1][0]  = fmaf(p0.y, wv[j].x, acc[1][0]);  acc[1][1]  = fmaf(p0.y, wv[j].y, acc[1][1]);
            acc[2][0]  = fmaf(p0.z, wv[j].x, acc[2][0]);  acc[2][1]  = fmaf(p0.z, wv[j].y, acc[2][1]);
            acc[3][0]  = fmaf(p0.w, wv[j].x, acc[3][0]);  acc[3][1]  = fmaf(p0.w, wv[j].y, acc[3][1]);
            acc[4][0]  = fmaf(p1.x, wv[j].x, acc[4][0]);  acc[4][1]  = fmaf(p1.x, wv[j].y, acc[4][1]);
            acc[5][0]  = fmaf(p1.y, wv[j].x, acc[5][0]);  acc[5][1]  = fmaf(p1.y, wv[j].y, acc[5][1]);
            acc[6][0]  = fmaf(p1.z, wv[j].x, acc[6][0]);  acc[6][1]  = fmaf(p1.z, wv[j].y, acc[6][1]);
            acc[7][0]  = fmaf(p1.w, wv[j].x, acc[7][0]);  acc[7][1]  = fmaf(p1.w, wv[j].y, acc[7][1]);
            acc[8][0]  = fmaf(p2.x, wv[j].x, acc[8][0]);  acc[8][1]  = fmaf(p2.x, wv[j].y, acc[8][1]);
            acc[9][0]  = fmaf(p2.y, wv[j].x, acc[9][0]);  acc[9][1]  = fmaf(p2.y, wv[j].y, acc[9][1]);
            acc[10][0] = fmaf(p2.z, wv[j].x, acc[10][0]); acc[10][1] = fmaf(p2.z, wv[j].y, acc[10][1]);
            acc[11][0] = fmaf(p2.w, wv[j].x, acc[11][0]); acc[11][1] = fmaf(p2.w, wv[j].y, acc[11][1]);
            acc[12][0] = fmaf(p3.x, wv[j].x, acc[12][0]); acc[12][1] = fmaf(p3.x, wv[j].y, acc[12][1]);
            acc[13][0] = fmaf(p3.y, wv[j].x, acc[13][0]); acc[13][1] = fmaf(p3.y, wv[j].y, acc[13][1]);
            acc[14][0] = fmaf(p3.z, wv[j].x, acc[14][0]); acc[14][1] = fmaf(p3.z, wv[j].y, acc[14][1]);
            acc[15][0] = fmaf(p3.w, wv[j].x, acc[15][0]); acc[15][1] = fmaf(p3.w, wv[j].y, acc[15][1]);
        }
    }
    // gumbel + scale
#pragma unroll
    for (int r = 0; r < 16; ++r) {
        float2 u = *reinterpret_cast<const float2*>(&gu[(size_t)(n0 + r) * HYP + c2]);
        float g0 = -logf(-logf(u.x + 1e-10f) + 1e-10f);
        float g1 = -logf(-logf(u.y + 1e-10f) + 1e-10f);
        acc[r][0] = (acc[r][0] + g0) * 2.0f;
        acc[r][1] = (acc[r][1] + g1) * 2.0f;
    }
    // row max
#pragma unroll
    for (int r = 0; r < 16; ++r) {
        float v = fmaxf(acc[r][0], acc[r][1]);
#pragma unroll
        for (int off = 32; off >= 1; off >>= 1) v = fmaxf(v, __shfl_xor(v, off));
        if (lane == 0) redA[w][r] = v;
    }
    __syncthreads();
#pragma unroll
    for (int r = 0; r < 16; ++r) {
        float m = fmaxf(redA[0][r], redA[1][r]);
        acc[r][0] = __expf(acc[r][0] - m);
        acc[r][1] = __expf(acc[r][1] - m);
        float v = acc[r][0] + acc[r][1];
#pragma unroll
        for (int off = 32; off >= 1; off >>= 1) v += __shfl_xor(v, off);
        if (lane == 0) redB[w][r] = v;
    }
    __syncthreads();
#pragma unroll
    for (int r = 0; r < 16; ++r) {
        float inv = 1.0f / (redB[0][r] + redB[1][r]);
        float2 o;
        o.x = acc[r][0] * inv;
        o.y = acc[r][1] * inv;
        *reinterpret_cast<float2*>(&Hm[(size_t)(n0 + r) * HYP + c2]) = o;
    }
}

// ---------------- lat = Hm^T @ x_emb (split-K, 64x64 tiles, atomic combine) ----------------

__global__ __launch_bounds__(256) void k_lat(const float* __restrict__ Hm, const float* __restrict__ x_emb,
                                             float* __restrict__ lat) {
    __shared__ float A[8 * 64];
    __shared__ float B[8 * 64];
    int bx = blockIdx.x;
    int tile = bx & 7;
    int kc = bx >> 3;
    int KC = (int)(gridDim.x >> 3);
    int h0 = (tile & 3) * 64;
    int d0 = (tile >> 2) * 64;
    int chunk = (N_NODES + KC - 1) / KC;
    int start = kc * chunk;
    int end = min(N_NODES, start + chunk);
    int tid = threadIdx.x;
    int hl = (tid & 15) * 4;
    int dl = (tid >> 4) * 4;
    float acc[16];
#pragma unroll
    for (int i = 0; i < 16; ++i) acc[i] = 0.0f;
    for (int n0 = start; n0 < end; n0 += 8) {
#pragma unroll
        for (int t = 0; t < 4; ++t) {
            int idx = tid + t * 256;
            int half = idx >> 9;
            int r = (idx >> 6) & 7;
            int c = idx & 63;
            int n = n0 + r;
            float v = 0.0f;
            if (n < end) v = half ? x_emb[(size_t)n * HID + d0 + c] : Hm[(size_t)n * HYP + h0 + c];
            if (half) B[r * 64 + c] = v;
            else A[r * 64 + c] = v;
        }
        __syncthreads();
#pragma unroll
        for (int r = 0; r < 8; ++r) {
            float4 av = *reinterpret_cast<const float4*>(&A[r * 64 + hl]);
            float4 bv = *reinterpret_cast<const float4*>(&B[r * 64 + dl]);
            float aa[4] = {av.x, av.y, av.z, av.w};
            float bb[4] = {bv.x, bv.y, bv.z, bv.w};
#pragma unroll
            for (int i = 0; i < 4; ++i)
#pragma unroll
                for (int j = 0; j < 4; ++j) acc[i * 4 + j] = fmaf(aa[i], bb[j], acc[i * 4 + j]);
        }
        __syncthreads();
    }
#pragma unroll
    for (int i = 0; i < 4; ++i)
#pragma unroll
        for (int j = 0; j < 4; ++j)
            atomicAdd(&lat[(size_t)(h0 + hl + i) * HID + (d0 + dl + j)], acc[i * 4 + j]);
}

// ---------------- tail: hyper_out = Hm @ lat; normalize; final; both ReLU heads ----------------

__global__ __launch_bounds__(128) void k_tail(const float* __restrict__ Hm, const float* __restrict__ lat,
                                              const float* __restrict__ accb,
                                              const float* __restrict__ wv, const float* __restrict__ bv,
                                              const float* __restrict__ wt, const float* __restrict__ bt,
                                              float* __restrict__ out_final, float* __restrict__ out_vis,
                                              float* __restrict__ out_txt) {
    __shared__ float hl[HYP * 16];  // [h][r], 16 KB
    __shared__ float fl[16 * HID];  // [r][k], 8 KB
    int n0 = blockIdx.x * 16;
    int tid = threadIdx.x;
    int lane = tid & 63;
    int w8 = (tid >> 6) * 8;  // this wave's row group
    int c2 = lane * 2;        // column pair
#pragma unroll
    for (int it = 0; it < 8; ++it) {
        int idx4 = tid + it * 128;  // 0..1023
        int r = idx4 & 15;
        int h4 = idx4 >> 4;         // 0..63
        float4 v = *reinterpret_cast<const float4*>(&Hm[(size_t)(n0 + r) * HYP + 4 * h4]);
        hl[(4 * h4 + 0) * 16 + r] = v.x;
        hl[(4 * h4 + 1) * 16 + r] = v.y;
        hl[(4 * h4 + 2) * 16 + r] = v.z;
        hl[(4 * h4 + 3) * 16 + r] = v.w;
    }
    __syncthreads();
    float acc[8][2];
#pragma unroll
    for (int r = 0; r < 8; ++r) { acc[r][0] = 0.0f; acc[r][1] = 0.0f; }
    for (int h = 0; h < HYP; h += 4) {
        float2 lv[4];
#pragma unroll
        for (int j = 0; j < 4; ++j)
            lv[j] = *reinterpret_cast<const float2*>(&lat[(size_t)(h + j) * HID + c2]);
#pragma unroll
        for (int j = 0; j < 4; ++j) {
            float4 p = *reinterpret_cast<const float4*>(&hl[(h + j) * 16 + w8]);
            float4 q = *reinterpret_cast<const float4*>(&hl[(h + j) * 16 + w8 + 4]);
            acc[0][0] = fmaf(p.x, lv[j].x, acc[0][0]); acc[0][1] = fmaf(p.x, lv[j].y, acc[0][1]);
            acc[1][0] = fmaf(p.y, lv[j].x, acc[1][0]); acc[1][1] = fmaf(p.y, lv[j].y, acc[1][1]);
            acc[2][0] = fmaf(p.z, lv[j].x, acc[2][0]); acc[2][1] = fmaf(p.z, lv[j].y, acc[2][1]);
            acc[3][0] = fmaf(p.w, lv[j].x, acc[3][0]); acc[3][1] = fmaf(p.w, lv[j].y, acc[3][1]);
            acc[4][0] = fmaf(q.x, lv[j].x, acc[4][0]); acc[4][1] = fmaf(q.x, lv[j].y, acc[4][1]);
            acc[5][0] = fmaf(q.y, lv[j].x, acc[5][0]); acc[5][1] = fmaf(q.y, lv[j].y, acc[5][1]);
            acc[6][0] = fmaf(q.z, lv[j].x, acc[6][0]); acc[6][1] = fmaf(q.z, lv[j].y, acc[6][1]);
            acc[7][0] = fmaf(q.w, lv[j].x, acc[7][0]); acc[7][1] = fmaf(q.w, lv[j].y, acc[7][1]);
        }
    }
    // per-row L2 norm: pure in-wave butterfly (each wave owns its 8 rows fully)
    float fin[8][2];
#pragma unroll
    for (int r = 0; r < 8; ++r) {
        float v = acc[r][0] * acc[r][0] + acc[r][1] * acc[r][1];
#pragma unroll
        for (int off = 32; off >= 1; off >>= 1) v += __shfl_xor(v, off);
        float inr = 1.0f / fmaxf(sqrtf(v), 1e-12f);
        size_t o = (size_t)(n0 + w8 + r) * HID + c2;
        float2 ab = *reinterpret_cast<const float2*>(&accb[o]);
        float2 f;
        f.x = ab.x * 0.25f + 0.1f * (acc[r][0] * inr);
        f.y = ab.y * 0.25f + 0.1f * (acc[r][1] * inr);
        fin[r][0] = f.x;
        fin[r][1] = f.y;
        *reinterpret_cast<float2*>(&out_final[o]) = f;
        *reinterpret_cast<float2*>(&fl[(w8 + r) * HID + c2]) = f;
    }
    __syncthreads();
    float av[8][2], at[8][2];
#pragma unroll
    for (int r = 0; r < 8; ++r) { av[r][0] = av[r][1] = at[r][0] = at[r][1] = 0.0f; }
    for (int k = 0; k < HID; k += 4) {
        float2 wvv[4], wtt[4];
#pragma unroll
        for (int j = 0; j < 4; ++j) {
            wvv[j] = *reinterpret_cast<const float2*>(&wv[(size_t)(k + j) * HID + c2]);
            wtt[j] = *reinterpret_cast<const float2*>(&wt[(size_t)(k + j) * HID + c2]);
        }
#pragma unroll
        for (int j = 0; j < 4; ++j) {
#pragma unroll
            for (int r = 0; r < 8; ++r) {
                float f = fl[(w8 + r) * HID + (k + j)];
                av[r][0] = fmaf(f, wvv[j].x, av[r][0]); av[r][1] = fmaf(f, wvv[j].y, av[r][1]);
                at[r][0] = fmaf(f, wtt[j].x, at[r][0]); at[r][1] = fmaf(f, wtt[j].y, at[r][1]);
            }
        }
    }
    float2 bvv = *reinterpret_cast<const float2*>(&bv[c2]);
    float2 btt = *reinterpret_cast<const float2*>(&bt[c2]);
#pragma unroll
    for (int r = 0; r < 8; ++r) {
        size_t o = (size_t)(n0 + w8 + r) * HID + c2;
        float2 ov, ot;
        ov.x = fmaxf(av[r][0] + bvv.x, 0.0f);
        ov.y = fmaxf(av[r][1] + bvv.y, 0.0f);
        ot.x = fmaxf(at[r][0] + btt.x, 0.0f);
        ot.y = fmaxf(at[r][1] + btt.y, 0.0f);
        *reinterpret_cast<float2*>(&out_vis[o]) = ov;
        *reinterpret_cast<float2*>(&out_txt[o]) = ot;
    }
}

// ---------------- launch ----------------

extern "C" void kernel_launch(void* const* d_in, const int* in_sizes, int n_in,
                              void* d_out, int out_size, void* d_ws, size_t ws_size,
                              hipStream_t stream) {
    const float* x      = (const float*)d_in[0];
    const int*   ei     = (const int*)d_in[1];
    const float* gu     = (const float*)d_in[2];
    const float* w_feat = (const float*)d_in[3];
    const float* b_feat = (const float*)d_in[4];
    const float* w_hyp  = (const float*)d_in[5];
    const float* w_vis  = (const float*)d_in[6];
    const float* b_vis  = (const float*)d_in[7];
    const float* w_txt  = (const float*)d_in[8];
    const float* b_txt  = (const float*)d_in[9];
    float* out = (float*)d_out;

    const int* srcv = ei;
    const int* dstv = ei + E_EDGES;

    char* p = (char*)d_ws;
    int*   deg     = (int*)p;   p += (size_t)N_NODES * 4;
    int*   cnt     = (int*)p;   p += (size_t)N_NODES * 4;
    float* lat     = (float*)p; p += (size_t)HYP * HID * 4;
    int*   rs      = (int*)p;   p += (size_t)(N_NODES + 1) * 4;
    float* dinv    = (float*)p; p += (size_t)N_NODES * 4;
    int*   csr_src = (int*)p;   p += (size_t)E_EDGES * 4;
    float* csr_w   = (float*)p; p += (size_t)E_EDGES * 4;
    float* x_emb   = (float*)p; p += (size_t)N_NODES * HID * 4;
    float* bufA    = (float*)p; p += (size_t)N_NODES * HID * 4;
    float* bufB    = (float*)p; p += (size_t)N_NODES * HID * 4;
    float* accb    = (float*)p; p += (size_t)N_NODES * HID * 4;
    float* Hm      = (float*)p; p += (size_t)N_NODES * HYP * 4;

    // zero: deg, cnt, lat (contiguous at the head of ws)
    (void)hipMemsetAsync(d_ws, 0, (size_t)(2 * N_NODES + HYP * HID) * 4, stream);

    k_deg<<<(E_EDGES + 255) / 256, 256, 0, stream>>>(dstv, deg);
    k_scan<<<1, 1024, 0, stream>>>(deg, rs, dinv);
    k_fill<<<(E_EDGES + 255) / 256, 256, 0, stream>>>(srcv, dstv, rs, cnt, dinv, csr_src, csr_w);
    k_emb<<<N_NODES / 16, 128, 0, stream>>>(x, w_feat, b_feat, x_emb, accb);
    k_prop<<<N_NODES / 4, 128, 0, stream>>>(x_emb, bufA, accb, rs, csr_src, csr_w);
    k_prop<<<N_NODES / 4, 128, 0, stream>>>(bufA, bufB, accb, rs, csr_src, csr_w);
    k_prop<<<N_NODES / 4, 128, 0, stream>>>(bufB, bufA, accb, rs, csr_src, csr_w);
    k_soft<<<N_NODES / 16, 128, 0, stream>>>(x_emb, w_hyp, gu, Hm);
    k_lat<<<8 * 128, 256, 0, stream>>>(Hm, x_emb, lat);
    k_tail<<<N_NODES / 16, 128, 0, stream>>>(Hm, lat, accb, w_vis, b_vis, w_txt, b_txt,
                                             out, out + (size_t)N_NODES * HID, out + (size_t)2 * N_NODES * HID);
}

// Round 5
// 842.493 us; speedup vs baseline: 1.2478x; 1.1519x over previous
//
#include <hip/hip_runtime.h>
#include <math.h>

#define N_NODES 50000
#define E_EDGES 600000
#define IN_DIM  384
#define HID     128
#define HYP     256

typedef __attribute__((ext_vector_type(8))) short bf16x8;
typedef __attribute__((ext_vector_type(4))) float f32x4;

__device__ __forceinline__ unsigned short f2bf(float f) {
    unsigned u = __builtin_bit_cast(unsigned, f);
    u = (u + 0x7FFFu + ((u >> 16) & 1u)) >> 16;
    return (unsigned short)u;
}

__device__ __forceinline__ bf16x8 cvt8(float4 p, float4 q) {
    bf16x8 a;
    a[0] = (short)f2bf(p.x); a[1] = (short)f2bf(p.y);
    a[2] = (short)f2bf(p.z); a[3] = (short)f2bf(p.w);
    a[4] = (short)f2bf(q.x); a[5] = (short)f2bf(q.y);
    a[6] = (short)f2bf(q.z); a[7] = (short)f2bf(q.w);
    return a;
}

// ---------------- graph preprocessing ----------------

__global__ void k_deg(const int* __restrict__ dst, int* __restrict__ deg) {
    int i = blockIdx.x * blockDim.x + threadIdx.x;
    if (i < E_EDGES) atomicAdd(&deg[dst[i]], 1);
}

__global__ __launch_bounds__(1024) void k_scan(const int* __restrict__ deg, int* __restrict__ row_start,
                                               float* __restrict__ dinv) {
    __shared__ int part[1024];
    int tid = threadIdx.x;
    const int chunk = (N_NODES + 1023) >> 10;  // 49
    int s = tid * chunk;
    int e = min(N_NODES, s + chunk);
    int sum = 0;
    for (int i = s; i < e; ++i) sum += deg[i];
    part[tid] = sum;
    __syncthreads();
    for (int off = 1; off < 1024; off <<= 1) {
        int t = (tid >= off) ? part[tid - off] : 0;
        __syncthreads();
        part[tid] += t;
        __syncthreads();
    }
    int base = part[tid] - sum;  // exclusive prefix
    for (int i = s; i < e; ++i) {
        int d = deg[i];
        row_start[i] = base;
        base += d;
        dinv[i] = (d > 0) ? rsqrtf((float)d) : 0.0f;
    }
    if (tid == 0) row_start[N_NODES] = E_EDGES;
}

__global__ void k_fill(const int* __restrict__ src, const int* __restrict__ dst,
                       const int* __restrict__ row_start, int* __restrict__ cnt,
                       const float* __restrict__ dinv,
                       int* __restrict__ csr_src, float* __restrict__ csr_w) {
    int i = blockIdx.x * blockDim.x + threadIdx.x;
    if (i < E_EDGES) {
        int d = dst[i], s = src[i];
        int pos = row_start[d] + atomicAdd(&cnt[d], 1);
        csr_src[pos] = s;
        csr_w[pos] = dinv[s] * dinv[d];
    }
}

// ---------------- transpose + fp32->bf16 convert: out[c][r] = bf16(in[r][c]) ----------------

__global__ void k_cvtT(const float* __restrict__ in, unsigned short* __restrict__ out, int R, int C) {
    int i = blockIdx.x * 256 + threadIdx.x;
    if (i < R * C) {
        int r = i / C;
        int c = i - r * C;
        out[(size_t)c * R + r] = f2bf(in[i]);
    }
}

// ---------------- x_emb = x @ w_feat + b : MFMA, 1 wave/block, 16 rows ----------------

__global__ __launch_bounds__(64) void k_emb(const float* __restrict__ x, const unsigned short* __restrict__ wfT,
                                            const float* __restrict__ bf_,
                                            float* __restrict__ x_emb, float* __restrict__ accb) {
    int lane = threadIdx.x & 63;
    int l16 = lane & 15, quad = lane >> 4;
    int m0 = blockIdx.x * 16;
    const float* xrow = x + (size_t)(m0 + l16) * IN_DIM + quad * 8;
    f32x4 acc[8];
#pragma unroll
    for (int nt = 0; nt < 8; ++nt) acc[nt] = (f32x4){0.f, 0.f, 0.f, 0.f};
#pragma unroll
    for (int kt = 0; kt < IN_DIM / 32; ++kt) {
        float4 p = *reinterpret_cast<const float4*>(xrow + kt * 32);
        float4 q = *reinterpret_cast<const float4*>(xrow + kt * 32 + 4);
        bf16x8 a = cvt8(p, q);
#pragma unroll
        for (int nt = 0; nt < 8; ++nt) {
            bf16x8 b = *reinterpret_cast<const bf16x8*>(&wfT[(size_t)(nt * 16 + l16) * IN_DIM + kt * 32 + quad * 8]);
            acc[nt] = __builtin_amdgcn_mfma_f32_16x16x32_bf16(a, b, acc[nt], 0, 0, 0);
        }
    }
#pragma unroll
    for (int nt = 0; nt < 8; ++nt) {
        int col = nt * 16 + l16;
        float bias = bf_[col];
#pragma unroll
        for (int r = 0; r < 4; ++r) {
            int row = m0 + quad * 4 + r;
            float v = acc[nt][r] + bias;
            size_t o = (size_t)row * HID + col;
            x_emb[o] = v;
            accb[o] = v;
        }
    }
}

// ---------------- one LightGCN layer (unchanged fp32 gather) ----------------

__device__ __forceinline__ void fma4(float4& a, const float4& v, float s) {
    a.x = fmaf(v.x, s, a.x);
    a.y = fmaf(v.y, s, a.y);
    a.z = fmaf(v.z, s, a.z);
    a.w = fmaf(v.w, s, a.w);
}

__global__ __launch_bounds__(128) void k_prop(const float* __restrict__ cur, float* __restrict__ nxt,
                                              float* __restrict__ accb,
                                              const int* __restrict__ row_start,
                                              const int* __restrict__ csr_src, const float* __restrict__ csr_w) {
    int tid = threadIdx.x;
    int n = blockIdx.x * 4 + (tid >> 5);
    int c4 = (tid & 31) * 4;
    int s = row_start[n];
    int e = row_start[n + 1];
    float4 a0 = {0.f, 0.f, 0.f, 0.f}, a1 = a0, a2 = a0, a3 = a0;
    int i = s;
    for (; i + 4 <= e; i += 4) {
        int s0 = csr_src[i], s1 = csr_src[i + 1], s2 = csr_src[i + 2], s3 = csr_src[i + 3];
        float w0 = csr_w[i], w1 = csr_w[i + 1], w2 = csr_w[i + 2], w3 = csr_w[i + 3];
        float4 v0 = *reinterpret_cast<const float4*>(&cur[(size_t)s0 * HID + c4]);
        float4 v1 = *reinterpret_cast<const float4*>(&cur[(size_t)s1 * HID + c4]);
        float4 v2 = *reinterpret_cast<const float4*>(&cur[(size_t)s2 * HID + c4]);
        float4 v3 = *reinterpret_cast<const float4*>(&cur[(size_t)s3 * HID + c4]);
        fma4(a0, v0, w0); fma4(a1, v1, w1); fma4(a2, v2, w2); fma4(a3, v3, w3);
    }
    for (; i < e; ++i) {
        int s0 = csr_src[i];
        float w0 = csr_w[i];
        float4 v0 = *reinterpret_cast<const float4*>(&cur[(size_t)s0 * HID + c4]);
        fma4(a0, v0, w0);
    }
    a0.x += a1.x + a2.x + a3.x;
    a0.y += a1.y + a2.y + a3.y;
    a0.z += a1.z + a2.z + a3.z;
    a0.w += a1.w + a2.w + a3.w;
    size_t o = (size_t)n * HID + c4;
    *reinterpret_cast<float4*>(&nxt[o]) = a0;
    float4 ac = *reinterpret_cast<const float4*>(&accb[o]);
    ac.x += a0.x; ac.y += a0.y; ac.z += a0.z; ac.w += a0.w;
    *reinterpret_cast<float4*>(&accb[o]) = ac;
}

// ---------------- Hm = softmax((x_emb @ w_hyper + g)/tau) : MFMA, 1 wave/block ----------------

__global__ __launch_bounds__(64) void k_soft(const float* __restrict__ x_emb, const unsigned short* __restrict__ whT,
                                             const float* __restrict__ gu, float* __restrict__ Hm) {
    int lane = threadIdx.x & 63;
    int l16 = lane & 15, quad = lane >> 4;
    int m0 = blockIdx.x * 16;
    const float* xrow = x_emb + (size_t)(m0 + l16) * HID + quad * 8;
    f32x4 acc[16];
#pragma unroll
    for (int nt = 0; nt < 16; ++nt) acc[nt] = (f32x4){0.f, 0.f, 0.f, 0.f};
#pragma unroll
    for (int kt = 0; kt < HID / 32; ++kt) {
        float4 p = *reinterpret_cast<const float4*>(xrow + kt * 32);
        float4 q = *reinterpret_cast<const float4*>(xrow + kt * 32 + 4);
        bf16x8 a = cvt8(p, q);
#pragma unroll
        for (int nt = 0; nt < 16; ++nt) {
            bf16x8 b = *reinterpret_cast<const bf16x8*>(&whT[(size_t)(nt * 16 + l16) * HID + kt * 32 + quad * 8]);
            acc[nt] = __builtin_amdgcn_mfma_f32_16x16x32_bf16(a, b, acc[nt], 0, 0, 0);
        }
    }
    // gumbel + 1/tau
#pragma unroll
    for (int nt = 0; nt < 16; ++nt) {
        int col = nt * 16 + l16;
#pragma unroll
        for (int r = 0; r < 4; ++r) {
            int row = m0 + quad * 4 + r;
            float u = gu[(size_t)row * HYP + col];
            float g = -logf(-logf(u + 1e-10f) + 1e-10f);
            acc[nt][r] = (acc[nt][r] + g) * 2.0f;
        }
    }
    // row max / sum over cols: per-lane over nt, then shfl over lane&15 group
    float mx[4] = {-3.4e38f, -3.4e38f, -3.4e38f, -3.4e38f};
#pragma unroll
    for (int nt = 0; nt < 16; ++nt)
#pragma unroll
        for (int r = 0; r < 4; ++r) mx[r] = fmaxf(mx[r], acc[nt][r]);
#pragma unroll
    for (int r = 0; r < 4; ++r) {
        mx[r] = fmaxf(mx[r], __shfl_xor(mx[r], 1));
        mx[r] = fmaxf(mx[r], __shfl_xor(mx[r], 2));
        mx[r] = fmaxf(mx[r], __shfl_xor(mx[r], 4));
        mx[r] = fmaxf(mx[r], __shfl_xor(mx[r], 8));
    }
    float sm[4] = {0.f, 0.f, 0.f, 0.f};
#pragma unroll
    for (int nt = 0; nt < 16; ++nt)
#pragma unroll
        for (int r = 0; r < 4; ++r) {
            float e = __expf(acc[nt][r] - mx[r]);
            acc[nt][r] = e;
            sm[r] += e;
        }
#pragma unroll
    for (int r = 0; r < 4; ++r) {
        sm[r] += __shfl_xor(sm[r], 1);
        sm[r] += __shfl_xor(sm[r], 2);
        sm[r] += __shfl_xor(sm[r], 4);
        sm[r] += __shfl_xor(sm[r], 8);
        sm[r] = 1.0f / sm[r];
    }
#pragma unroll
    for (int nt = 0; nt < 16; ++nt) {
        int col = nt * 16 + l16;
#pragma unroll
        for (int r = 0; r < 4; ++r)
            Hm[(size_t)(m0 + quad * 4 + r) * HYP + col] = acc[nt][r] * sm[r];
    }
}

// ---------------- lat = Hm^T @ x_emb (split-K fp32, unchanged) ----------------

__global__ __launch_bounds__(256) void k_lat(const float* __restrict__ Hm, const float* __restrict__ x_emb,
                                             float* __restrict__ lat) {
    __shared__ float A[8 * 64];
    __shared__ float B[8 * 64];
    int bx = blockIdx.x;
    int tile = bx & 7;
    int kc = bx >> 3;
    int KC = (int)(gridDim.x >> 3);
    int h0 = (tile & 3) * 64;
    int d0 = (tile >> 2) * 64;
    int chunk = (N_NODES + KC - 1) / KC;
    int start = kc * chunk;
    int end = min(N_NODES, start + chunk);
    int tid = threadIdx.x;
    int hl = (tid & 15) * 4;
    int dl = (tid >> 4) * 4;
    float acc[16];
#pragma unroll
    for (int i = 0; i < 16; ++i) acc[i] = 0.0f;
    for (int n0 = start; n0 < end; n0 += 8) {
#pragma unroll
        for (int t = 0; t < 4; ++t) {
            int idx = tid + t * 256;
            int half = idx >> 9;
            int r = (idx >> 6) & 7;
            int c = idx & 63;
            int n = n0 + r;
            float v = 0.0f;
            if (n < end) v = half ? x_emb[(size_t)n * HID + d0 + c] : Hm[(size_t)n * HYP + h0 + c];
            if (half) B[r * 64 + c] = v;
            else A[r * 64 + c] = v;
        }
        __syncthreads();
#pragma unroll
        for (int r = 0; r < 8; ++r) {
            float4 av = *reinterpret_cast<const float4*>(&A[r * 64 + hl]);
            float4 bv = *reinterpret_cast<const float4*>(&B[r * 64 + dl]);
            float aa[4] = {av.x, av.y, av.z, av.w};
            float bb[4] = {bv.x, bv.y, bv.z, bv.w};
#pragma unroll
            for (int i = 0; i < 4; ++i)
#pragma unroll
                for (int j = 0; j < 4; ++j) acc[i * 4 + j] = fmaf(aa[i], bb[j], acc[i * 4 + j]);
        }
        __syncthreads();
    }
#pragma unroll
    for (int i = 0; i < 4; ++i)
#pragma unroll
        for (int j = 0; j < 4; ++j)
            atomicAdd(&lat[(size_t)(h0 + hl + i) * HID + (d0 + dl + j)], acc[i * 4 + j]);
}

// ---------------- tail: hyper = Hm @ lat; norm; final; two head GEMMs — MFMA, 1 wave/block ----------------

__global__ __launch_bounds__(64) void k_tail(const float* __restrict__ Hm, const unsigned short* __restrict__ latT,
                                             const float* __restrict__ accb,
                                             const unsigned short* __restrict__ wvT, const float* __restrict__ bv,
                                             const unsigned short* __restrict__ wtT, const float* __restrict__ bt,
                                             float* __restrict__ out_final, float* __restrict__ out_vis,
                                             float* __restrict__ out_txt) {
    __shared__ unsigned short fl[16 * HID];  // final tile, bf16, 4 KB
    int lane = threadIdx.x & 63;
    int l16 = lane & 15, quad = lane >> 4;
    int m0 = blockIdx.x * 16;
    const float* hrow = Hm + (size_t)(m0 + l16) * HYP + quad * 8;
    f32x4 acc[8];
#pragma unroll
    for (int nt = 0; nt < 8; ++nt) acc[nt] = (f32x4){0.f, 0.f, 0.f, 0.f};
#pragma unroll
    for (int kt = 0; kt < HYP / 32; ++kt) {
        float4 p = *reinterpret_cast<const float4*>(hrow + kt * 32);
        float4 q = *reinterpret_cast<const float4*>(hrow + kt * 32 + 4);
        bf16x8 a = cvt8(p, q);
#pragma unroll
        for (int nt = 0; nt < 8; ++nt) {
            bf16x8 b = *reinterpret_cast<const bf16x8*>(&latT[(size_t)(nt * 16 + l16) * HYP + kt * 32 + quad * 8]);
            acc[nt] = __builtin_amdgcn_mfma_f32_16x16x32_bf16(a, b, acc[nt], 0, 0, 0);
        }
    }
    // per-row L2 norm: rows = m0 + quad*4 + r; reduce over cols = nt x (lane&15)
    float ss[4] = {0.f, 0.f, 0.f, 0.f};
#pragma unroll
    for (int nt = 0; nt < 8; ++nt)
#pragma unroll
        for (int r = 0; r < 4; ++r) ss[r] = fmaf(acc[nt][r], acc[nt][r], ss[r]);
#pragma unroll
    for (int r = 0; r < 4; ++r) {
        ss[r] += __shfl_xor(ss[r], 1);
        ss[r] += __shfl_xor(ss[r], 2);
        ss[r] += __shfl_xor(ss[r], 4);
        ss[r] += __shfl_xor(ss[r], 8);
        ss[r] = 1.0f / fmaxf(sqrtf(ss[r]), 1e-12f);
    }
    // final = accb/4 + 0.1 * normalized; store + stage bf16 tile for head GEMMs
#pragma unroll
    for (int nt = 0; nt < 8; ++nt) {
        int col = nt * 16 + l16;
#pragma unroll
        for (int r = 0; r < 4; ++r) {
            int lrow = quad * 4 + r;
            size_t o = (size_t)(m0 + lrow) * HID + col;
            float f = accb[o] * 0.25f + 0.1f * (acc[nt][r] * ss[r]);
            out_final[o] = f;
            fl[lrow * HID + col] = f2bf(f);
        }
    }
    __syncthreads();
    // heads: A = final tile (LDS), B = wvT / wtT
    f32x4 av[8], at4[8];
#pragma unroll
    for (int nt = 0; nt < 8; ++nt) {
        av[nt] = (f32x4){0.f, 0.f, 0.f, 0.f};
        at4[nt] = (f32x4){0.f, 0.f, 0.f, 0.f};
    }
#pragma unroll
    for (int kt = 0; kt < HID / 32; ++kt) {
        bf16x8 a = *reinterpret_cast<const bf16x8*>(&fl[l16 * HID + kt * 32 + quad * 8]);
#pragma unroll
        for (int nt = 0; nt < 8; ++nt) {
            bf16x8 b1 = *reinterpret_cast<const bf16x8*>(&wvT[(size_t)(nt * 16 + l16) * HID + kt * 32 + quad * 8]);
            bf16x8 b2 = *reinterpret_cast<const bf16x8*>(&wtT[(size_t)(nt * 16 + l16) * HID + kt * 32 + quad * 8]);
            av[nt] = __builtin_amdgcn_mfma_f32_16x16x32_bf16(a, b1, av[nt], 0, 0, 0);
            at4[nt] = __builtin_amdgcn_mfma_f32_16x16x32_bf16(a, b2, at4[nt], 0, 0, 0);
        }
    }
#pragma unroll
    for (int nt = 0; nt < 8; ++nt) {
        int col = nt * 16 + l16;
        float b1 = bv[col], b2 = bt[col];
#pragma unroll
        for (int r = 0; r < 4; ++r) {
            size_t o = (size_t)(m0 + quad * 4 + r) * HID + col;
            out_vis[o] = fmaxf(av[nt][r] + b1, 0.0f);
            out_txt[o] = fmaxf(at4[nt][r] + b2, 0.0f);
        }
    }
}

// ---------------- launch ----------------

extern "C" void kernel_launch(void* const* d_in, const int* in_sizes, int n_in,
                              void* d_out, int out_size, void* d_ws, size_t ws_size,
                              hipStream_t stream) {
    const float* x      = (const float*)d_in[0];
    const int*   ei     = (const int*)d_in[1];
    const float* gu     = (const float*)d_in[2];
    const float* w_feat = (const float*)d_in[3];
    const float* b_feat = (const float*)d_in[4];
    const float* w_hyp  = (const float*)d_in[5];
    const float* w_vis  = (const float*)d_in[6];
    const float* b_vis  = (const float*)d_in[7];
    const float* w_txt  = (const float*)d_in[8];
    const float* b_txt  = (const float*)d_in[9];
    float* out = (float*)d_out;

    const int* srcv = ei;
    const int* dstv = ei + E_EDGES;

    char* p = (char*)d_ws;
    int*   deg     = (int*)p;   p += (size_t)N_NODES * 4;
    int*   cnt     = (int*)p;   p += (size_t)N_NODES * 4;
    float* lat     = (float*)p; p += (size_t)HYP * HID * 4;
    int*   rs      = (int*)p;   p += (size_t)(N_NODES + 1) * 4;
    float* dinv    = (float*)p; p += (size_t)N_NODES * 4;
    int*   csr_src = (int*)p;   p += (size_t)E_EDGES * 4;
    float* csr_w   = (float*)p; p += (size_t)E_EDGES * 4;
    float* x_emb   = (float*)p; p += (size_t)N_NODES * HID * 4;
    float* bufA    = (float*)p; p += (size_t)N_NODES * HID * 4;
    float* bufB    = (float*)p; p += (size_t)N_NODES * HID * 4;
    float* accb    = (float*)p; p += (size_t)N_NODES * HID * 4;
    float* Hm      = (float*)p; p += (size_t)N_NODES * HYP * 4;
    unsigned short* wfT  = (unsigned short*)p; p += (size_t)HID * IN_DIM * 2;  // [128][384]
    unsigned short* whT  = (unsigned short*)p; p += (size_t)HYP * HID * 2;     // [256][128]
    unsigned short* wvT  = (unsigned short*)p; p += (size_t)HID * HID * 2;     // [128][128]
    unsigned short* wtT  = (unsigned short*)p; p += (size_t)HID * HID * 2;     // [128][128]
    unsigned short* latT = (unsigned short*)p; p += (size_t)HID * HYP * 2;     // [128][256]

    // zero: deg, cnt, lat (contiguous at the head of ws)
    (void)hipMemsetAsync(d_ws, 0, (size_t)(2 * N_NODES + HYP * HID) * 4, stream);

    // weight transposes/converts (independent of graph work)
    k_cvtT<<<(IN_DIM * HID + 255) / 256, 256, 0, stream>>>(w_feat, wfT, IN_DIM, HID);
    k_cvtT<<<(HID * HYP + 255) / 256, 256, 0, stream>>>(w_hyp, whT, HID, HYP);
    k_cvtT<<<(HID * HID + 255) / 256, 256, 0, stream>>>(w_vis, wvT, HID, HID);
    k_cvtT<<<(HID * HID + 255) / 256, 256, 0, stream>>>(w_txt, wtT, HID, HID);

    k_deg<<<(E_EDGES + 255) / 256, 256, 0, stream>>>(dstv, deg);
    k_scan<<<1, 1024, 0, stream>>>(deg, rs, dinv);
    k_fill<<<(E_EDGES + 255) / 256, 256, 0, stream>>>(srcv, dstv, rs, cnt, dinv, csr_src, csr_w);

    k_emb<<<N_NODES / 16, 64, 0, stream>>>(x, wfT, b_feat, x_emb, accb);
    k_prop<<<N_NODES / 4, 128, 0, stream>>>(x_emb, bufA, accb, rs, csr_src, csr_w);
    k_prop<<<N_NODES / 4, 128, 0, stream>>>(bufA, bufB, accb, rs, csr_src, csr_w);
    k_prop<<<N_NODES / 4, 128, 0, stream>>>(bufB, bufA, accb, rs, csr_src, csr_w);
    k_soft<<<N_NODES / 16, 64, 0, stream>>>(x_emb, whT, gu, Hm);
    k_lat<<<8 * 128, 256, 0, stream>>>(Hm, x_emb, lat);
    k_cvtT<<<(HYP * HID + 255) / 256, 256, 0, stream>>>(lat, latT, HYP, HID);
    k_tail<<<N_NODES / 16, 64, 0, stream>>>(Hm, latT, accb, wvT, b_vis, wtT, b_txt,
                                            out, out + (size_t)N_NODES * HID, out + (size_t)2 * N_NODES * HID);
}